// Round 2
// baseline (31684.604 us; speedup 1.0000x reference)
//
#include <hip/hip_runtime.h>
#include <stdint.h>
#include <stddef.h>

typedef _Float16 f16;
typedef _Float16 half2_t __attribute__((ext_vector_type(2)));
typedef _Float16 half8_t __attribute__((ext_vector_type(8)));
typedef float   float4_t __attribute__((ext_vector_type(4)));

#define T_STEPS 8192

// ---------------- workspace layout (bytes) ----------------
#define OFF_ZX   ((size_t)0)                    // Zx0  f16 [8192][4096]      = 67108864
#define OFF_WSW  ((size_t)67108864)             // WSW  u32 [256][256][96]    = 25165824
#define OFF_HS   (OFF_WSW + (size_t)25165824)   // hs   f16 [8192][1024]      = 16777216
#define OFF_H0R  (OFF_HS + (size_t)16777216)    // H0 ring u64 [4][512]       = 16384
#define OFF_H1R  (OFF_H0R + (size_t)16384)      // H1 ring u64 [4][512]       = 16384
// total ~ 104 MiB

__device__ __forceinline__ uint32_t packh(float a, float b) {
  half2_t h; h.x = (_Float16)a; h.y = (_Float16)b;
  return __builtin_bit_cast(uint32_t, h);
}

__device__ __forceinline__ float fdot2w(uint32_t w, uint32_t h, float c) {
#if __has_builtin(__builtin_amdgcn_fdot2)
  return __builtin_amdgcn_fdot2(__builtin_bit_cast(half2_t, w),
                                __builtin_bit_cast(half2_t, h), c, false);
#else
  half2_t a = __builtin_bit_cast(half2_t, w);
  half2_t b = __builtin_bit_cast(half2_t, h);
  return c + (float)a.x * (float)b.x + (float)a.y * (float)b.y;
#endif
}

__device__ __forceinline__ uint64_t ald64(const uint64_t* p) {
  return __hip_atomic_load(p, __ATOMIC_RELAXED, __HIP_MEMORY_SCOPE_AGENT);
}
__device__ __forceinline__ void ast64(uint64_t* p, uint64_t v) {
  __hip_atomic_store(p, v, __ATOMIC_RELAXED, __HIP_MEMORY_SCOPE_AGENT);
}

__device__ __forceinline__ float sigf(float x) { return 1.f / (1.f + __expf(-x)); }
__device__ __forceinline__ float tanhf_(float x) { return 2.f * sigf(2.f * x) - 1.f; }

// ---------------- init: zero tag rings ----------------
__global__ void k_init(uint64_t* __restrict__ H0, uint64_t* __restrict__ H1) {
  int i = blockIdx.x * blockDim.x + threadIdx.x;
  if (i < 4 * 512) { H0[i] = 0ull; H1[i] = 0ull; }
}

// ---------------- pack recurrent weights into per-thread f16 pairs ----------------
// block b owns h0/h1 outputs 4b..4b+3. wave w = gate g. thread lane l, word p
// covers ADJACENT column pair (2k, 2k+1) with k = l + 64p (matches ring format).
// word idx: L0 rr*8+p, L1ih 32+, L1hh 64+.
__global__ void k_prep_w(const float* __restrict__ whh0, const float* __restrict__ wih1,
                         const float* __restrict__ whh1, uint32_t* __restrict__ WSW) {
  int b = blockIdx.x, tid = threadIdx.x;
  int w = tid >> 6, l = tid & 63;
  uint32_t* dst = WSW + ((size_t)b * 256 + tid) * 96;
#pragma unroll
  for (int rr = 0; rr < 4; ++rr) {
    size_t R = (size_t)(4 * b + rr + 1024 * w) * 1024;
#pragma unroll
    for (int p = 0; p < 8; ++p) {
      int k = l + 64 * p;
      int c0 = 2 * k, c1 = 2 * k + 1;
      dst[rr * 8 + p]      = packh(whh0[R + c0], whh0[R + c1]);
      dst[32 + rr * 8 + p] = packh(wih1[R + c0], wih1[R + c1]);
      dst[64 + rr * 8 + p] = packh(whh1[R + c0], whh1[R + c1]);
    }
  }
}

// ---------------- generic 128x128 MFMA f16 GEMM: C[m][n] = A[m][:]·B[n][:] + bias(n) ----------------
// A: f32 or f16 [M][lda]; B: f32 [N][K] (row-major, i.e. B^T w.r.t. the product).
template <bool A16, bool OUT16>
__global__ __launch_bounds__(256) void k_gemm(const void* __restrict__ Ap,
                                              const float* __restrict__ B,
                                              const float* __restrict__ bias0,
                                              const float* __restrict__ bias1,
                                              void* __restrict__ Cp,
                                              int N, int K, int lda) {
  __shared__ __align__(16) f16 As[128 * 40];
  __shared__ __align__(16) f16 Bs[128 * 40];
  int bn = blockIdx.x * 128, bm = blockIdx.y * 128;
  int tid = threadIdx.x;
  int w = tid >> 6, l = tid & 63;
  int m0w = (w >> 1) * 64, n0w = (w & 1) * 64;
  int lr = l & 15, q = l >> 4;
  int srow = tid >> 1, skoff = (tid & 1) * 16;

  float4_t acc[4][4];
#pragma unroll
  for (int i = 0; i < 4; ++i)
#pragma unroll
    for (int j = 0; j < 4; ++j) acc[i][j] = (float4_t){0.f, 0.f, 0.f, 0.f};

  for (int kt = 0; kt < K; kt += 32) {
    __syncthreads();
    // stage A
    if (A16) {
      const f16* Ah = (const f16*)Ap + (size_t)(bm + srow) * lda + kt + skoff;
      uint4 u0 = *(const uint4*)Ah;
      uint4 u1 = *(const uint4*)(Ah + 8);
      *(uint4*)&As[srow * 40 + skoff] = u0;
      *(uint4*)&As[srow * 40 + skoff + 8] = u1;
    } else {
      const float* Af = (const float*)Ap + (size_t)(bm + srow) * lda + kt + skoff;
      const float4_t* A4 = (const float4_t*)Af;
      float4_t f0 = A4[0], f1 = A4[1], f2 = A4[2], f3 = A4[3];
      half8_t h0 = {(f16)f0.x, (f16)f0.y, (f16)f0.z, (f16)f0.w,
                    (f16)f1.x, (f16)f1.y, (f16)f1.z, (f16)f1.w};
      half8_t h1 = {(f16)f2.x, (f16)f2.y, (f16)f2.z, (f16)f2.w,
                    (f16)f3.x, (f16)f3.y, (f16)f3.z, (f16)f3.w};
      *(half8_t*)&As[srow * 40 + skoff] = h0;
      *(half8_t*)&As[srow * 40 + skoff + 8] = h1;
    }
    // stage B (always f32)
    {
      const float* Bf = B + (size_t)(bn + srow) * K + kt + skoff;
      const float4_t* B4 = (const float4_t*)Bf;
      float4_t f0 = B4[0], f1 = B4[1], f2 = B4[2], f3 = B4[3];
      half8_t h0 = {(f16)f0.x, (f16)f0.y, (f16)f0.z, (f16)f0.w,
                    (f16)f1.x, (f16)f1.y, (f16)f1.z, (f16)f1.w};
      half8_t h1 = {(f16)f2.x, (f16)f2.y, (f16)f2.z, (f16)f2.w,
                    (f16)f3.x, (f16)f3.y, (f16)f3.z, (f16)f3.w};
      *(half8_t*)&Bs[srow * 40 + skoff] = h0;
      *(half8_t*)&Bs[srow * 40 + skoff + 8] = h1;
    }
    __syncthreads();
    half8_t af[4], bf[4];
#pragma unroll
    for (int i = 0; i < 4; ++i) af[i] = *(const half8_t*)&As[(m0w + 16 * i + lr) * 40 + q * 8];
#pragma unroll
    for (int j = 0; j < 4; ++j) bf[j] = *(const half8_t*)&Bs[(n0w + 16 * j + lr) * 40 + q * 8];
#pragma unroll
    for (int i = 0; i < 4; ++i)
#pragma unroll
      for (int j = 0; j < 4; ++j)
        acc[i][j] = __builtin_amdgcn_mfma_f32_16x16x32_f16(af[i], bf[j], acc[i][j], 0, 0, 0);
  }

  // epilogue: C/D layout col = lane&15, row = (lane>>4)*4 + reg
#pragma unroll
  for (int j = 0; j < 4; ++j) {
    int n = bn + n0w + 16 * j + lr;
    float bv = bias0 ? bias0[n] : 0.f;
    if (bias1) bv += bias1[n];
#pragma unroll
    for (int i = 0; i < 4; ++i) {
#pragma unroll
      for (int r = 0; r < 4; ++r) {
        int m = bm + m0w + 16 * i + q * 4 + r;
        float v = acc[i][j][r] + bv;
        if (OUT16) ((f16*)Cp)[(size_t)m * N + n] = (f16)v;
        else       ((float*)Cp)[(size_t)m * N + n] = v;
      }
    }
  }
}

// ---------------- persistent serial LSTM kernel ----------------
// 256 blocks x 256 threads. Phase t computes layer0 step t and layer1 step t-1.
// Sync is data-as-flag: ring entry = u64 {tag = phase+1, 2xf16 h}. Consumers
// poll the entries directly (agent-scope atomics through LLC); no counters.
__global__ __launch_bounds__(256, 1) void k_serial(
    const f16* __restrict__ Zx, const uint32_t* __restrict__ WSW,
    uint64_t* __restrict__ H0, uint64_t* __restrict__ H1, f16* __restrict__ hs,
    const float* __restrict__ b_ih1, const float* __restrict__ b_hh1) {
  __shared__ __align__(16) uint32_t h0L[512];
  __shared__ __align__(16) uint32_t h1L[512];
  __shared__ __align__(16) float red[48 * 20];
  __shared__ float zarr[48];

  int b = blockIdx.x, tid = threadIdx.x;
  int w = tid >> 6, l = tid & 63;

  // persistent per-thread weights: 96 dwords (f16x2)
  uint32_t wreg[96];
  {
    const uint4* src = (const uint4*)(WSW + ((size_t)b * 256 + tid) * 96);
#pragma unroll
    for (int q = 0; q < 24; ++q) {
      uint4 u = src[q];
      wreg[4 * q + 0] = u.x; wreg[4 * q + 1] = u.y;
      wreg[4 * q + 2] = u.z; wreg[4 * q + 3] = u.w;
    }
  }
  float c0 = 0.f, c1 = 0.f;
  float b1v[4] = {0.f, 0.f, 0.f, 0.f};
  if (tid >= 4 && tid < 8) {
    int j = tid - 4;
#pragma unroll
    for (int g = 0; g < 4; ++g) {
      int R = 4 * b + j + 1024 * g;
      b1v[g] = b_ih1[R] + b_hh1[R];
    }
  }

  // Zx preload for phase 0 (16 gate-row values for this block)
  f16 zx_pref = (f16)0.f;
  if (tid < 16) {
    int j = tid & 3, g = tid >> 2;
    zx_pref = Zx[(size_t)0 * 4096 + 4 * b + j + 1024 * g];
  }

  for (int t = 0; t <= T_STEPS; ++t) {
    float zxv = (t < T_STEPS) ? (float)zx_pref : 0.f;
    // ---- prefetch Zx for next phase BEFORE polling (hides HBM latency) ----
    f16 zx_nx = (f16)0.f;
    if (t + 1 < T_STEPS && tid < 16) {
      int j = tid & 3, g = tid >> 2;
      zx_nx = Zx[(size_t)(t + 1) * 4096 + 4 * b + j + 1024 * g];
    }

    // ---- 1. poll tagged ring entries (h0_{t-1}, h1_{t-2}); 4 disjoint u64/thread ----
    {
      const uint32_t tg = (uint32_t)t;
      const uint64_t* p0 = &H0[(size_t)(t & 3) * 512 + tid];
      const uint64_t* p1 = p0 + 256;
      const uint64_t* p2 = &H1[(size_t)(t & 3) * 512 + tid];
      const uint64_t* p3 = p2 + 256;
      uint64_t v0, v1, v2, v3;
      for (;;) {
        v0 = ald64(p0); v1 = ald64(p1); v2 = ald64(p2); v3 = ald64(p3);
        if ((uint32_t)(v0 >> 32) == tg && (uint32_t)(v1 >> 32) == tg &&
            (uint32_t)(v2 >> 32) == tg && (uint32_t)(v3 >> 32) == tg) break;
      }
      h0L[tid]       = (uint32_t)v0;
      h0L[tid + 256] = (uint32_t)v1;
      h1L[tid]       = (uint32_t)v2;
      h1L[tid + 256] = (uint32_t)v3;
    }
    __syncthreads();

    // ---- 2. partial dot products (weights in VGPRs) ----
    uint32_t h0w[8], h1w[8];
#pragma unroll
    for (int p = 0; p < 8; ++p) { h0w[p] = h0L[64 * p + l]; h1w[p] = h1L[64 * p + l]; }
    float acc0[4], accA[4], accB[4];
#pragma unroll
    for (int rr = 0; rr < 4; ++rr) { acc0[rr] = 0.f; accA[rr] = 0.f; accB[rr] = 0.f; }
#pragma unroll
    for (int rr = 0; rr < 4; ++rr) {
#pragma unroll
      for (int p = 0; p < 8; ++p) {
        acc0[rr] = fdot2w(wreg[rr * 8 + p],      h0w[p], acc0[rr]);
        accA[rr] = fdot2w(wreg[32 + rr * 8 + p], h0w[p], accA[rr]);
        accB[rr] = fdot2w(wreg[64 + rr * 8 + p], h1w[p], accB[rr]);
      }
    }
    // butterfly fold lanes {l, l^1, l^2} -> 16 column-groups
#pragma unroll
    for (int rr = 0; rr < 4; ++rr) {
      acc0[rr] += __shfl_xor(acc0[rr], 1); acc0[rr] += __shfl_xor(acc0[rr], 2);
      accA[rr] += __shfl_xor(accA[rr], 1); accA[rr] += __shfl_xor(accA[rr], 2);
      accB[rr] += __shfl_xor(accB[rr], 1); accB[rr] += __shfl_xor(accB[rr], 2);
    }
    if ((l & 3) == 0) {
      int g = l >> 2;
#pragma unroll
      for (int rr = 0; rr < 4; ++rr) {
        red[(4 * w + rr) * 20 + g]        = acc0[rr];
        red[(16 + 4 * w + rr) * 20 + g]   = accA[rr];
        red[(32 + 4 * w + rr) * 20 + g]   = accB[rr];
      }
    }
    __syncthreads();

    // ---- 3. final reduce: 48 rows x 16 groups ----
    if (tid < 48) {
      const float4_t* rp = (const float4_t*)&red[tid * 20];
      float4_t s4 = rp[0];
      s4 += rp[1]; s4 += rp[2]; s4 += rp[3];
      float s = s4.x + s4.y + s4.z + s4.w;
      if (tid < 16) s += zxv;
      zarr[tid] = s;
    }
    __syncthreads();

    // ---- 4. gates (torch order i,f,g,o) + tagged ring stores ----
    if (tid < 8) {
      float h = 0.f;
      bool st = false;
      if (tid < 4) {
        if (t < T_STEPS) {
          int j = tid;
          float zi = zarr[j], zf = zarr[4 + j], zg = zarr[8 + j], zo = zarr[12 + j];
          float ig = sigf(zi), fg = sigf(zf), gg = tanhf_(zg), og = sigf(zo);
          c0 = fg * c0 + ig * gg;
          h = og * tanhf_(c0);
          st = true;
        }
      } else {
        int j = tid - 4;
        if (t > 0) {
          float zi = zarr[16 + j]      + zarr[32 + j]      + b1v[0];
          float zf = zarr[16 + 4 + j]  + zarr[32 + 4 + j]  + b1v[1];
          float zg = zarr[16 + 8 + j]  + zarr[32 + 8 + j]  + b1v[2];
          float zo = zarr[16 + 12 + j] + zarr[32 + 12 + j] + b1v[3];
          float ig = sigf(zi), fg = sigf(zf), gg = tanhf_(zg), og = sigf(zo);
          c1 = fg * c1 + ig * gg;
          h = og * tanhf_(c1);
          hs[(size_t)(t - 1) * 1024 + 4 * b + j] = (f16)h;
        }
        st = true;  // at t==0 stores h1 init state (zeros) with tag 1
      }
      float ho = __shfl_xor(h, 1);
      if (st && !(tid & 1)) {
        uint32_t pair = packh(h, ho);
        uint64_t val = ((uint64_t)(uint32_t)(t + 1) << 32) | (uint64_t)pair;
        uint64_t* ring = (tid < 4) ? H0 : H1;
        ast64(&ring[(size_t)((t + 1) & 3) * 512 + 2 * b + ((tid >> 1) & 1)], val);
      }
    }
    zx_pref = zx_nx;
  }
}

// ---------------- value head: v[t] = hs[t]·w_val + b_val ----------------
__global__ void k_values(const f16* __restrict__ hs, const float* __restrict__ w_val,
                         const float* __restrict__ b_val, float* __restrict__ outv) {
  int t = blockIdx.x * 4 + (threadIdx.x >> 6);
  int l = threadIdx.x & 63;
  const f16* row = hs + (size_t)t * 1024 + l * 16;
  const float* wv = w_val + l * 16;
  float s = 0.f;
#pragma unroll
  for (int i = 0; i < 16; ++i) s += (float)row[i] * wv[i];
#pragma unroll
  for (int d = 1; d < 64; d <<= 1) s += __shfl_xor(s, d);
  if (l == 0) outv[t] = s + b_val[0];
}

// ---------------- softmax over 512 logits per row, in place ----------------
__global__ void k_softmax(float* __restrict__ out) {
  int t = blockIdx.x * 4 + (threadIdx.x >> 6);
  int l = threadIdx.x & 63;
  float* row = out + (size_t)t * 512;
  float v[8];
  float m = -1e30f;
#pragma unroll
  for (int i = 0; i < 8; ++i) { v[i] = row[l + 64 * i]; m = fmaxf(m, v[i]); }
#pragma unroll
  for (int d = 1; d < 64; d <<= 1) m = fmaxf(m, __shfl_xor(m, d));
  float s = 0.f;
#pragma unroll
  for (int i = 0; i < 8; ++i) { v[i] = __expf(v[i] - m); s += v[i]; }
#pragma unroll
  for (int d = 1; d < 64; d <<= 1) s += __shfl_xor(s, d);
  float inv = 1.f / s;
#pragma unroll
  for (int i = 0; i < 8; ++i) row[l + 64 * i] = v[i] * inv;
}

extern "C" void kernel_launch(void* const* d_in, const int* in_sizes, int n_in,
                              void* d_out, int out_size, void* d_ws, size_t ws_size,
                              hipStream_t stream) {
  const float* x      = (const float*)d_in[0];
  const float* w_ih0  = (const float*)d_in[1];
  const float* w_hh0  = (const float*)d_in[2];
  const float* b_ih0  = (const float*)d_in[3];
  const float* b_hh0  = (const float*)d_in[4];
  const float* w_ih1  = (const float*)d_in[5];
  const float* w_hh1  = (const float*)d_in[6];
  const float* b_ih1  = (const float*)d_in[7];
  const float* b_hh1  = (const float*)d_in[8];
  const float* w_pol  = (const float*)d_in[9];
  const float* b_pol  = (const float*)d_in[10];
  const float* w_val  = (const float*)d_in[11];
  const float* b_val  = (const float*)d_in[12];

  char* ws = (char*)d_ws;
  f16*      Zx  = (f16*)(ws + OFF_ZX);
  uint32_t* WSW = (uint32_t*)(ws + OFF_WSW);
  f16*      hs  = (f16*)(ws + OFF_HS);
  uint64_t* H0  = (uint64_t*)(ws + OFF_H0R);
  uint64_t* H1  = (uint64_t*)(ws + OFF_H1R);
  float*    out = (float*)d_out;

  k_init<<<8, 256, 0, stream>>>(H0, H1);
  k_prep_w<<<256, 256, 0, stream>>>(w_hh0, w_ih1, w_hh1, WSW);
  // Zx0 = x @ w_ih0^T + b_ih0 + b_hh0 : M=8192, N=4096, K=512
  k_gemm<false, true><<<dim3(32, 64), 256, 0, stream>>>(
      (const void*)x, w_ih0, b_ih0, b_hh0, (void*)Zx, 4096, 512, 512);
  k_serial<<<256, 256, 0, stream>>>(Zx, WSW, H0, H1, hs, b_ih1, b_hh1);
  // policy logits = hs @ w_pol^T + b_pol : M=8192, N=512, K=1024 -> d_out (f32)
  k_gemm<true, false><<<dim3(4, 64), 256, 0, stream>>>(
      (const void*)hs, w_pol, b_pol, nullptr, (void*)out, 512, 1024, 1024);
  k_values<<<2048, 256, 0, stream>>>(hs, w_val, b_val, out + (size_t)8192 * 512);
  k_softmax<<<2048, 256, 0, stream>>>(out);
}

// Round 3
// 29255.832 us; speedup vs baseline: 1.0830x; 1.0830x over previous
//
#include <hip/hip_runtime.h>
#include <stdint.h>
#include <stddef.h>

typedef _Float16 f16;
typedef _Float16 half2_t __attribute__((ext_vector_type(2)));
typedef _Float16 half8_t __attribute__((ext_vector_type(8)));
typedef float   float4_t __attribute__((ext_vector_type(4)));
typedef float   float2_t __attribute__((ext_vector_type(2)));

#define T_STEPS 8192
#define NREP 16

// ---------------- workspace layout (bytes) ----------------
#define OFF_ZX   ((size_t)0)                    // Zx0  f16 [8192][4096]      = 67108864
#define OFF_HS   ((size_t)67108864)             // hs   f16 [8192][1024]      = 16777216
#define OFF_RING (OFF_HS + (size_t)16777216)    // ring u64 [16][4][1024]     = 524288
// total ~ 80.5 MiB

__device__ __forceinline__ uint32_t packh(float a, float b) {
  half2_t h; h.x = (_Float16)a; h.y = (_Float16)b;
  return __builtin_bit_cast(uint32_t, h);
}

__device__ __forceinline__ float fdot2w(uint32_t w, uint32_t h, float c) {
#if __has_builtin(__builtin_amdgcn_fdot2)
  return __builtin_amdgcn_fdot2(__builtin_bit_cast(half2_t, w),
                                __builtin_bit_cast(half2_t, h), c, false);
#else
  half2_t a = __builtin_bit_cast(half2_t, w);
  half2_t b = __builtin_bit_cast(half2_t, h);
  return c + (float)a.x * (float)b.x + (float)a.y * (float)b.y;
#endif
}

__device__ __forceinline__ uint64_t ald64(const uint64_t* p) {
  return __hip_atomic_load(p, __ATOMIC_RELAXED, __HIP_MEMORY_SCOPE_AGENT);
}
__device__ __forceinline__ void ast64(uint64_t* p, uint64_t v) {
  __hip_atomic_store(p, v, __ATOMIC_RELAXED, __HIP_MEMORY_SCOPE_AGENT);
}

__device__ __forceinline__ float sigf(float x) { return 1.f / (1.f + __expf(-x)); }
__device__ __forceinline__ float tanhf_(float x) { return 2.f * sigf(2.f * x) - 1.f; }

// ---------------- init: zero tagged replica rings ----------------
__global__ void k_init(uint64_t* __restrict__ RING) {
  int i = blockIdx.x * blockDim.x + threadIdx.x;
  if (i < NREP * 4 * 1024) RING[i] = 0ull;
}

// ---------------- generic 128x128 MFMA f16 GEMM: C[m][n] = A[m][:]·B[n][:] + bias(n) ----------------
// A: f32 or f16 [M][lda]; B: f32 [N][K] (row-major, i.e. B^T w.r.t. the product).
template <bool A16, bool OUT16>
__global__ __launch_bounds__(256) void k_gemm(const void* __restrict__ Ap,
                                              const float* __restrict__ B,
                                              const float* __restrict__ bias0,
                                              const float* __restrict__ bias1,
                                              void* __restrict__ Cp,
                                              int N, int K, int lda) {
  __shared__ __align__(16) f16 As[128 * 40];
  __shared__ __align__(16) f16 Bs[128 * 40];
  int bn = blockIdx.x * 128, bm = blockIdx.y * 128;
  int tid = threadIdx.x;
  int w = tid >> 6, l = tid & 63;
  int m0w = (w >> 1) * 64, n0w = (w & 1) * 64;
  int lr = l & 15, q = l >> 4;
  int srow = tid >> 1, skoff = (tid & 1) * 16;

  float4_t acc[4][4];
#pragma unroll
  for (int i = 0; i < 4; ++i)
#pragma unroll
    for (int j = 0; j < 4; ++j) acc[i][j] = (float4_t){0.f, 0.f, 0.f, 0.f};

  for (int kt = 0; kt < K; kt += 32) {
    __syncthreads();
    if (A16) {
      const f16* Ah = (const f16*)Ap + (size_t)(bm + srow) * lda + kt + skoff;
      uint4 u0 = *(const uint4*)Ah;
      uint4 u1 = *(const uint4*)(Ah + 8);
      *(uint4*)&As[srow * 40 + skoff] = u0;
      *(uint4*)&As[srow * 40 + skoff + 8] = u1;
    } else {
      const float* Af = (const float*)Ap + (size_t)(bm + srow) * lda + kt + skoff;
      const float4_t* A4 = (const float4_t*)Af;
      float4_t f0 = A4[0], f1 = A4[1], f2 = A4[2], f3 = A4[3];
      half8_t h0 = {(f16)f0.x, (f16)f0.y, (f16)f0.z, (f16)f0.w,
                    (f16)f1.x, (f16)f1.y, (f16)f1.z, (f16)f1.w};
      half8_t h1 = {(f16)f2.x, (f16)f2.y, (f16)f2.z, (f16)f2.w,
                    (f16)f3.x, (f16)f3.y, (f16)f3.z, (f16)f3.w};
      *(half8_t*)&As[srow * 40 + skoff] = h0;
      *(half8_t*)&As[srow * 40 + skoff + 8] = h1;
    }
    {
      const float* Bf = B + (size_t)(bn + srow) * K + kt + skoff;
      const float4_t* B4 = (const float4_t*)Bf;
      float4_t f0 = B4[0], f1 = B4[1], f2 = B4[2], f3 = B4[3];
      half8_t h0 = {(f16)f0.x, (f16)f0.y, (f16)f0.z, (f16)f0.w,
                    (f16)f1.x, (f16)f1.y, (f16)f1.z, (f16)f1.w};
      half8_t h1 = {(f16)f2.x, (f16)f2.y, (f16)f2.z, (f16)f2.w,
                    (f16)f3.x, (f16)f3.y, (f16)f3.z, (f16)f3.w};
      *(half8_t*)&Bs[srow * 40 + skoff] = h0;
      *(half8_t*)&Bs[srow * 40 + skoff + 8] = h1;
    }
    __syncthreads();
    half8_t af[4], bf[4];
#pragma unroll
    for (int i = 0; i < 4; ++i) af[i] = *(const half8_t*)&As[(m0w + 16 * i + lr) * 40 + q * 8];
#pragma unroll
    for (int j = 0; j < 4; ++j) bf[j] = *(const half8_t*)&Bs[(n0w + 16 * j + lr) * 40 + q * 8];
#pragma unroll
    for (int i = 0; i < 4; ++i)
#pragma unroll
      for (int j = 0; j < 4; ++j)
        acc[i][j] = __builtin_amdgcn_mfma_f32_16x16x32_f16(af[i], bf[j], acc[i][j], 0, 0, 0);
  }

#pragma unroll
  for (int j = 0; j < 4; ++j) {
    int n = bn + n0w + 16 * j + lr;
    float bv = bias0 ? bias0[n] : 0.f;
    if (bias1) bv += bias1[n];
#pragma unroll
    for (int i = 0; i < 4; ++i) {
#pragma unroll
      for (int r = 0; r < 4; ++r) {
        int m = bm + m0w + 16 * i + q * 4 + r;
        float v = acc[i][j][r] + bv;
        if (OUT16) ((f16*)Cp)[(size_t)m * N + n] = (f16)v;
        else       ((float*)Cp)[(size_t)m * N + n] = v;
      }
    }
  }
}

// ---------------- persistent serial LSTM kernel ----------------
// 256 blocks x 256 threads. Phase t computes layer0 step t and layer1 step t-1.
// Sync: tagged data words in 16 REPLICA rings (producer fans out 64 stores via
// wave-0 lanes); consumer polls only replica (b&15) -> 16 readers/line.
__global__ __launch_bounds__(256, 1) void k_serial(
    const f16* __restrict__ Zx,
    const float* __restrict__ whh0, const float* __restrict__ wih1,
    const float* __restrict__ whh1,
    uint64_t* __restrict__ RING, f16* __restrict__ hs,
    const float* __restrict__ b_ih1, const float* __restrict__ b_hh1) {
  __shared__ __align__(16) uint32_t h0L[512];
  __shared__ __align__(16) uint32_t h1L[512];
  __shared__ float zarr[32];

  int b = blockIdx.x, tid = threadIdx.x;
  int w = tid >> 6, l = tid & 63;

  // pack persistent per-thread weights straight from f32 sources.
  // word p covers adjacent column pair (2k, 2k+1), k = l + 64p.
  // rows: gate = w, output = 4b+rr.
  uint32_t wreg[96];
#pragma unroll
  for (int rr = 0; rr < 4; ++rr) {
    size_t R = (size_t)(4 * b + rr + 1024 * w) * 1024;
#pragma unroll
    for (int p = 0; p < 8; ++p) {
      int k = l + 64 * p;
      float2_t u0 = *(const float2_t*)&whh0[R + 2 * k];
      float2_t u1 = *(const float2_t*)&wih1[R + 2 * k];
      float2_t u2 = *(const float2_t*)&whh1[R + 2 * k];
      wreg[rr * 8 + p]      = packh(u0.x, u0.y);
      wreg[32 + rr * 8 + p] = packh(u1.x, u1.y);
      wreg[64 + rr * 8 + p] = packh(u2.x, u2.y);
    }
  }

  float c0 = 0.f, c1 = 0.f;
  float b1v[4] = {0.f, 0.f, 0.f, 0.f};
  if (tid >= 4 && tid < 8) {
    int j = tid - 4;
#pragma unroll
    for (int g = 0; g < 4; ++g) {
      int R = 4 * b + j + 1024 * g;
      b1v[g] = b_ih1[R] + b_hh1[R];
    }
  }

  const uint64_t* myrep = RING + (size_t)(b & (NREP - 1)) * 4 * 1024;

  // Zx preload for phase 0: lane 0 of wave w loads gate-w's 4 consecutive f16.
  uint64_t zxq = 0;
  if (l == 0) zxq = *(const uint64_t*)(Zx + (size_t)0 * 4096 + 1024 * w + 4 * b);

  for (int t = 0; t <= T_STEPS; ++t) {
    // ---- prefetch Zx for next phase BEFORE polling ----
    uint64_t zxq_nx = 0;
    if (t + 1 < T_STEPS && l == 0)
      zxq_nx = *(const uint64_t*)(Zx + (size_t)(t + 1) * 4096 + 1024 * w + 4 * b);

    // ---- 1. poll tagged entries in my replica (selective re-poll) ----
    {
      const uint32_t tg = (uint32_t)t;
      const uint64_t* base = myrep + (size_t)(t & 3) * 1024;
      const uint64_t* p0 = base + tid;
      const uint64_t* p1 = base + tid + 256;
      const uint64_t* p2 = base + 512 + tid;
      const uint64_t* p3 = base + 512 + tid + 256;
      uint64_t v0 = 0, v1 = 0, v2 = 0, v3 = 0;
      bool d0 = false, d1 = false, d2 = false, d3 = false;
      do {
        if (!d0) { v0 = ald64(p0); d0 = ((uint32_t)(v0 >> 32) == tg); }
        if (!d1) { v1 = ald64(p1); d1 = ((uint32_t)(v1 >> 32) == tg); }
        if (!d2) { v2 = ald64(p2); d2 = ((uint32_t)(v2 >> 32) == tg); }
        if (!d3) { v3 = ald64(p3); d3 = ((uint32_t)(v3 >> 32) == tg); }
      } while (!(d0 && d1 && d2 && d3));
      h0L[tid]       = (uint32_t)v0;
      h0L[tid + 256] = (uint32_t)v1;
      h1L[tid]       = (uint32_t)v2;
      h1L[tid + 256] = (uint32_t)v3;
    }
    __syncthreads();

    // ---- 2. partial dot products (weights in registers) ----
    uint32_t h0w[8], h1w[8];
#pragma unroll
    for (int p = 0; p < 8; ++p) { h0w[p] = h0L[64 * p + l]; h1w[p] = h1L[64 * p + l]; }
    float acc0[4], accA[4], accB[4];
#pragma unroll
    for (int rr = 0; rr < 4; ++rr) { acc0[rr] = 0.f; accA[rr] = 0.f; accB[rr] = 0.f; }
#pragma unroll
    for (int rr = 0; rr < 4; ++rr) {
#pragma unroll
      for (int p = 0; p < 8; ++p) {
        acc0[rr] = fdot2w(wreg[rr * 8 + p],      h0w[p], acc0[rr]);
        accA[rr] = fdot2w(wreg[32 + rr * 8 + p], h0w[p], accA[rr]);
        accB[rr] = fdot2w(wreg[64 + rr * 8 + p], h1w[p], accB[rr]);
      }
    }
    // full-wave butterfly fold: every lane ends with the row sum
#pragma unroll
    for (int d = 1; d < 64; d <<= 1) {
#pragma unroll
      for (int rr = 0; rr < 4; ++rr) {
        acc0[rr] += __shfl_xor(acc0[rr], d);
        accA[rr] += __shfl_xor(accA[rr], d);
        accB[rr] += __shfl_xor(accB[rr], d);
      }
    }
    if (l == 0) {
      float zx0 = 0.f, zx1 = 0.f, zx2 = 0.f, zx3 = 0.f;
      if (t < T_STEPS) {
        half2_t za = __builtin_bit_cast(half2_t, (uint32_t)(zxq & 0xffffffffull));
        half2_t zb = __builtin_bit_cast(half2_t, (uint32_t)(zxq >> 32));
        zx0 = (float)za.x; zx1 = (float)za.y; zx2 = (float)zb.x; zx3 = (float)zb.y;
      }
      zarr[4 * w + 0] = acc0[0] + zx0;
      zarr[4 * w + 1] = acc0[1] + zx1;
      zarr[4 * w + 2] = acc0[2] + zx2;
      zarr[4 * w + 3] = acc0[3] + zx3;
#pragma unroll
      for (int rr = 0; rr < 4; ++rr) zarr[16 + 4 * w + rr] = accA[rr] + accB[rr];
    }
    __syncthreads();

    // ---- 3. gates (wave 0 only; waves 1-3 run ahead into next poll) ----
    if (w == 0) {
      float h = 0.f;
      if (tid < 4) {
        if (t < T_STEPS) {
          int j = tid;
          float zi = zarr[j], zf = zarr[4 + j], zg = zarr[8 + j], zo = zarr[12 + j];
          float ig = sigf(zi), fg = sigf(zf), gg = tanhf_(zg), og = sigf(zo);
          c0 = fg * c0 + ig * gg;
          h = og * tanhf_(c0);
        }
      } else if (tid < 8) {
        if (t > 0) {
          int j = tid - 4;
          float zi = zarr[16 + j]      + b1v[0];
          float zf = zarr[16 + 4 + j]  + b1v[1];
          float zg = zarr[16 + 8 + j]  + b1v[2];
          float zo = zarr[16 + 12 + j] + b1v[3];
          float ig = sigf(zi), fg = sigf(zf), gg = tanhf_(zg), og = sigf(zo);
          c1 = fg * c1 + ig * gg;
          h = og * tanhf_(c1);
          hs[(size_t)(t - 1) * 1024 + 4 * b + tid - 4] = (f16)h;
        }
      }
      // pack pairs in even lanes 0,2 (h0) and 4,6 (h1); fan out to 16 replicas
      float ho = __shfl_xor(h, 1);
      uint64_t val = ((uint64_t)(uint32_t)(t + 1) << 32) | (uint64_t)packh(h, ho);
      uint64_t bc = __shfl(val, 2 * (tid & 3));
      int rep = tid >> 2, e = tid & 3;
      int ent = (e < 2) ? (2 * b + e) : (512 + 2 * b + (e - 2));
      ast64(&RING[((size_t)rep * 4 + (size_t)((t + 1) & 3)) * 1024 + ent], bc);
    }
    zxq = zxq_nx;
  }
}

// ---------------- value head: v[t] = hs[t]·w_val + b_val ----------------
__global__ void k_values(const f16* __restrict__ hs, const float* __restrict__ w_val,
                         const float* __restrict__ b_val, float* __restrict__ outv) {
  int t = blockIdx.x * 4 + (threadIdx.x >> 6);
  int l = threadIdx.x & 63;
  const f16* row = hs + (size_t)t * 1024 + l * 16;
  const float* wv = w_val + l * 16;
  float s = 0.f;
#pragma unroll
  for (int i = 0; i < 16; ++i) s += (float)row[i] * wv[i];
#pragma unroll
  for (int d = 1; d < 64; d <<= 1) s += __shfl_xor(s, d);
  if (l == 0) outv[t] = s + b_val[0];
}

// ---------------- softmax over 512 logits per row, in place ----------------
__global__ void k_softmax(float* __restrict__ out) {
  int t = blockIdx.x * 4 + (threadIdx.x >> 6);
  int l = threadIdx.x & 63;
  float* row = out + (size_t)t * 512;
  float v[8];
  float m = -1e30f;
#pragma unroll
  for (int i = 0; i < 8; ++i) { v[i] = row[l + 64 * i]; m = fmaxf(m, v[i]); }
#pragma unroll
  for (int d = 1; d < 64; d <<= 1) m = fmaxf(m, __shfl_xor(m, d));
  float s = 0.f;
#pragma unroll
  for (int i = 0; i < 8; ++i) { v[i] = __expf(v[i] - m); s += v[i]; }
#pragma unroll
  for (int d = 1; d < 64; d <<= 1) s += __shfl_xor(s, d);
  float inv = 1.f / s;
#pragma unroll
  for (int i = 0; i < 8; ++i) row[l + 64 * i] = v[i] * inv;
}

extern "C" void kernel_launch(void* const* d_in, const int* in_sizes, int n_in,
                              void* d_out, int out_size, void* d_ws, size_t ws_size,
                              hipStream_t stream) {
  const float* x      = (const float*)d_in[0];
  const float* w_ih0  = (const float*)d_in[1];
  const float* w_hh0  = (const float*)d_in[2];
  const float* b_ih0  = (const float*)d_in[3];
  const float* b_hh0  = (const float*)d_in[4];
  const float* w_ih1  = (const float*)d_in[5];
  const float* w_hh1  = (const float*)d_in[6];
  const float* b_ih1  = (const float*)d_in[7];
  const float* b_hh1  = (const float*)d_in[8];
  const float* w_pol  = (const float*)d_in[9];
  const float* b_pol  = (const float*)d_in[10];
  const float* w_val  = (const float*)d_in[11];
  const float* b_val  = (const float*)d_in[12];

  char* ws = (char*)d_ws;
  f16*      Zx   = (f16*)(ws + OFF_ZX);
  f16*      hs   = (f16*)(ws + OFF_HS);
  uint64_t* RING = (uint64_t*)(ws + OFF_RING);
  float*    out  = (float*)d_out;

  k_init<<<256, 256, 0, stream>>>(RING);
  // Zx0 = x @ w_ih0^T + b_ih0 + b_hh0 : M=8192, N=4096, K=512
  k_gemm<false, true><<<dim3(32, 64), 256, 0, stream>>>(
      (const void*)x, w_ih0, b_ih0, b_hh0, (void*)Zx, 4096, 512, 512);
  k_serial<<<256, 256, 0, stream>>>(Zx, w_hh0, w_ih1, w_hh1, RING, hs, b_ih1, b_hh1);
  // policy logits = hs @ w_pol^T + b_pol : M=8192, N=512, K=1024 -> d_out (f32)
  k_gemm<true, false><<<dim3(4, 64), 256, 0, stream>>>(
      (const void*)hs, w_pol, b_pol, nullptr, (void*)out, 512, 1024, 1024);
  k_values<<<2048, 256, 0, stream>>>(hs, w_val, b_val, out + (size_t)8192 * 512);
  k_softmax<<<2048, 256, 0, stream>>>(out);
}

// Round 4
// 23469.440 us; speedup vs baseline: 1.3500x; 1.2466x over previous
//
#include <hip/hip_runtime.h>
#include <stdint.h>
#include <stddef.h>

typedef _Float16 f16;
typedef _Float16 half2_t __attribute__((ext_vector_type(2)));
typedef _Float16 half8_t __attribute__((ext_vector_type(8)));
typedef float   float4_t __attribute__((ext_vector_type(4)));
typedef float   float2_t __attribute__((ext_vector_type(2)));

#define T_STEPS 8192
#define L0_BLOCKS 128

// ---------------- workspace layout (bytes) ----------------
#define OFF_ZX   ((size_t)0)                    // Zx0  f16 [8192][4096]      = 67108864
#define OFF_HS   ((size_t)67108864)             // hs   f16 [8192][1024]      = 16777216
#define OFF_R0   (OFF_HS + (size_t)16777216)    // R0 u64 [16][4][512]        = 262144
#define OFF_R1   (OFF_R0 + (size_t)262144)      // R1 u64 [8][4][512]         = 131072
// total ~ 80.3 MiB

__device__ __forceinline__ uint32_t packh(float a, float b) {
  half2_t h; h.x = (_Float16)a; h.y = (_Float16)b;
  return __builtin_bit_cast(uint32_t, h);
}

__device__ __forceinline__ float fdot2w(uint32_t w, uint32_t h, float c) {
#if __has_builtin(__builtin_amdgcn_fdot2)
  return __builtin_amdgcn_fdot2(__builtin_bit_cast(half2_t, w),
                                __builtin_bit_cast(half2_t, h), c, false);
#else
  half2_t a = __builtin_bit_cast(half2_t, w);
  half2_t b = __builtin_bit_cast(half2_t, h);
  return c + (float)a.x * (float)b.x + (float)a.y * (float)b.y;
#endif
}

__device__ __forceinline__ uint64_t ald64(const uint64_t* p) {
  return __hip_atomic_load(p, __ATOMIC_RELAXED, __HIP_MEMORY_SCOPE_AGENT);
}
__device__ __forceinline__ void ast64(uint64_t* p, uint64_t v) {
  __hip_atomic_store(p, v, __ATOMIC_RELAXED, __HIP_MEMORY_SCOPE_AGENT);
}

__device__ __forceinline__ float sigf(float x) { return 1.f / (1.f + __expf(-x)); }
__device__ __forceinline__ float tanhf_(float x) { return 2.f * sigf(2.f * x) - 1.f; }

// ---------------- init: zero both tagged replica rings (contiguous) ----------------
__global__ void k_init(uint64_t* __restrict__ R) {
  int i = blockIdx.x * blockDim.x + threadIdx.x;
  if (i < (16 + 8) * 4 * 512) R[i] = 0ull;
}

// ---------------- generic 128x128 MFMA f16 GEMM (unchanged from R3) ----------------
template <bool A16, bool OUT16>
__global__ __launch_bounds__(256) void k_gemm(const void* __restrict__ Ap,
                                              const float* __restrict__ B,
                                              const float* __restrict__ bias0,
                                              const float* __restrict__ bias1,
                                              void* __restrict__ Cp,
                                              int N, int K, int lda) {
  __shared__ __align__(16) f16 As[128 * 40];
  __shared__ __align__(16) f16 Bs[128 * 40];
  int bn = blockIdx.x * 128, bm = blockIdx.y * 128;
  int tid = threadIdx.x;
  int w = tid >> 6, l = tid & 63;
  int m0w = (w >> 1) * 64, n0w = (w & 1) * 64;
  int lr = l & 15, q = l >> 4;
  int srow = tid >> 1, skoff = (tid & 1) * 16;

  float4_t acc[4][4];
#pragma unroll
  for (int i = 0; i < 4; ++i)
#pragma unroll
    for (int j = 0; j < 4; ++j) acc[i][j] = (float4_t){0.f, 0.f, 0.f, 0.f};

  for (int kt = 0; kt < K; kt += 32) {
    __syncthreads();
    if (A16) {
      const f16* Ah = (const f16*)Ap + (size_t)(bm + srow) * lda + kt + skoff;
      uint4 u0 = *(const uint4*)Ah;
      uint4 u1 = *(const uint4*)(Ah + 8);
      *(uint4*)&As[srow * 40 + skoff] = u0;
      *(uint4*)&As[srow * 40 + skoff + 8] = u1;
    } else {
      const float* Af = (const float*)Ap + (size_t)(bm + srow) * lda + kt + skoff;
      const float4_t* A4 = (const float4_t*)Af;
      float4_t f0 = A4[0], f1 = A4[1], f2 = A4[2], f3 = A4[3];
      half8_t h0 = {(f16)f0.x, (f16)f0.y, (f16)f0.z, (f16)f0.w,
                    (f16)f1.x, (f16)f1.y, (f16)f1.z, (f16)f1.w};
      half8_t h1 = {(f16)f2.x, (f16)f2.y, (f16)f2.z, (f16)f2.w,
                    (f16)f3.x, (f16)f3.y, (f16)f3.z, (f16)f3.w};
      *(half8_t*)&As[srow * 40 + skoff] = h0;
      *(half8_t*)&As[srow * 40 + skoff + 8] = h1;
    }
    {
      const float* Bf = B + (size_t)(bn + srow) * K + kt + skoff;
      const float4_t* B4 = (const float4_t*)Bf;
      float4_t f0 = B4[0], f1 = B4[1], f2 = B4[2], f3 = B4[3];
      half8_t h0 = {(f16)f0.x, (f16)f0.y, (f16)f0.z, (f16)f0.w,
                    (f16)f1.x, (f16)f1.y, (f16)f1.z, (f16)f1.w};
      half8_t h1 = {(f16)f2.x, (f16)f2.y, (f16)f2.z, (f16)f2.w,
                    (f16)f3.x, (f16)f3.y, (f16)f3.z, (f16)f3.w};
      *(half8_t*)&Bs[srow * 40 + skoff] = h0;
      *(half8_t*)&Bs[srow * 40 + skoff + 8] = h1;
    }
    __syncthreads();
    half8_t af[4], bf[4];
#pragma unroll
    for (int i = 0; i < 4; ++i) af[i] = *(const half8_t*)&As[(m0w + 16 * i + lr) * 40 + q * 8];
#pragma unroll
    for (int j = 0; j < 4; ++j) bf[j] = *(const half8_t*)&Bs[(n0w + 16 * j + lr) * 40 + q * 8];
#pragma unroll
    for (int i = 0; i < 4; ++i)
#pragma unroll
      for (int j = 0; j < 4; ++j)
        acc[i][j] = __builtin_amdgcn_mfma_f32_16x16x32_f16(af[i], bf[j], acc[i][j], 0, 0, 0);
  }

#pragma unroll
  for (int j = 0; j < 4; ++j) {
    int n = bn + n0w + 16 * j + lr;
    float bv = bias0 ? bias0[n] : 0.f;
    if (bias1) bv += bias1[n];
#pragma unroll
    for (int i = 0; i < 4; ++i) {
#pragma unroll
      for (int r = 0; r < 4; ++r) {
        int m = bm + m0w + 16 * i + q * 4 + r;
        float v = acc[i][j][r] + bv;
        if (OUT16) ((f16*)Cp)[(size_t)m * N + n] = (f16)v;
        else       ((float*)Cp)[(size_t)m * N + n] = v;
      }
    }
  }
}

// ---------------- persistent serial LSTM: two 128-block sync domains ----------------
// Blocks 0..127   = layer 0: phase t computes h0(t) from h0(t-1), Zx(t).
// Blocks 128..255 = layer 1: phase t computes h1(t) from h0(t), h1(t-1).
// Ring entry = u64 { tag , 2xf16 }.  h(tau) carries tag tau+1 in slot (tau+1)&3.
// R0 replicas 0-7 -> L0 consumers, 8-15 -> L1 consumers. R1 replicas 0-7 -> L1.
// L0 lag-checks one R1 entry (tag >= t-1) => ring-depth-4 clobber safety.
__global__ __launch_bounds__(256, 1) void k_serial(
    const f16* __restrict__ Zx,
    const float* __restrict__ whh0, const float* __restrict__ wih1,
    const float* __restrict__ whh1,
    uint64_t* __restrict__ R0, uint64_t* __restrict__ R1, f16* __restrict__ hs,
    const float* __restrict__ b_ih1, const float* __restrict__ b_hh1) {
  __shared__ __align__(8) uint32_t hL[1024];
  __shared__ uint32_t pairs[4];

  int tid = threadIdx.x, w = tid >> 6, l = tid & 63;

  if (blockIdx.x < L0_BLOCKS) {
    // ================= layer 0 =================
    int b = blockIdx.x;
    // weights: 8 rows (4 gates x 2 outputs) x 8 f16-pairs per lane
    uint32_t wr[64];
#pragma unroll
    for (int g = 0; g < 4; ++g)
#pragma unroll
      for (int o = 0; o < 2; ++o) {
        size_t R = (size_t)(1024 * g + 8 * b + 2 * w + o) * 1024;
#pragma unroll
        for (int p = 0; p < 8; ++p) {
          int k = l + 64 * p;
          float2_t u = *(const float2_t*)&whh0[R + 2 * k];
          wr[(2 * g + o) * 8 + p] = packh(u.x, u.y);
        }
      }
    float c0 = 0.f;
    float zx[4] = {0.f, 0.f, 0.f, 0.f};
    if (l < 2) {
#pragma unroll
      for (int g = 0; g < 4; ++g)
        zx[g] = (float)Zx[(size_t)1024 * g + 8 * b + 2 * w + l];
    }

    for (int t = 0; t < T_STEPS; ++t) {
      // prefetch next Zx before polling (hides HBM latency under the wait)
      float zxn[4] = {0.f, 0.f, 0.f, 0.f};
      if (l < 2 && t + 1 < T_STEPS) {
#pragma unroll
        for (int g = 0; g < 4; ++g)
          zxn[g] = (float)Zx[(size_t)(t + 1) * 4096 + 1024 * g + 8 * b + 2 * w + l];
      }
      // lag check: one h1 tag >= t-1 keeps depth-4 ring safe for L1 consumers
      if (tid == 0 && t >= 2) {
        const uint64_t* lp =
            R1 + ((size_t)(b & 7) * 4 + (size_t)((t - 1) & 3)) * 512 + ((4 * b) & 511);
        while ((int)(uint32_t)(ald64(lp) >> 32) < t - 1) {}
      }
      // poll own domain: h0(t-1) = tag t, slot t&3; entries tid, tid+256
      {
        const uint64_t* base = R0 + ((size_t)(b & 7) * 4 + (size_t)(t & 3)) * 512;
        uint64_t v0 = 0, v1 = 0;
        bool d0 = false, d1 = false;
        do {
          if (!d0) { v0 = ald64(base + tid);       d0 = ((uint32_t)(v0 >> 32) == (uint32_t)t); }
          if (!d1) { v1 = ald64(base + tid + 256); d1 = ((uint32_t)(v1 >> 32) == (uint32_t)t); }
        } while (!(d0 && d1));
        hL[tid] = (uint32_t)v0;
        hL[tid + 256] = (uint32_t)v1;
      }
      __syncthreads();

      uint32_t hw[8];
#pragma unroll
      for (int p = 0; p < 8; ++p) hw[p] = hL[l + 64 * p];
      float acc[8];
#pragma unroll
      for (int ri = 0; ri < 8; ++ri) acc[ri] = 0.f;
#pragma unroll
      for (int ri = 0; ri < 8; ++ri)
#pragma unroll
        for (int p = 0; p < 8; ++p) acc[ri] = fdot2w(wr[ri * 8 + p], hw[p], acc[ri]);
#pragma unroll
      for (int d = 1; d < 64; d <<= 1)
#pragma unroll
        for (int ri = 0; ri < 8; ++ri) acc[ri] += __shfl_xor(acc[ri], d);

      float h = 0.f;
      if (l < 2) {
        float zi = acc[0 + l] + zx[0];
        float zf = acc[2 + l] + zx[1];
        float zg = acc[4 + l] + zx[2];
        float zo = acc[6 + l] + zx[3];
        float ig = sigf(zi), fg = sigf(zf), gg = tanhf_(zg), og = sigf(zo);
        c0 = fg * c0 + ig * gg;
        h = og * tanhf_(c0);
      }
      float ho = __shfl(h, 1);
      if (l == 0) pairs[w] = packh(h, ho);
      __syncthreads();
      if (w == 0) {
        uint64_t val = ((uint64_t)(uint32_t)(t + 1) << 32) | (uint64_t)pairs[l & 3];
        ast64(&R0[((size_t)(l >> 2) * 4 + (size_t)((t + 1) & 3)) * 512 + 4 * b + (l & 3)], val);
      }
#pragma unroll
      for (int g = 0; g < 4; ++g) zx[g] = zxn[g];
    }
  } else {
    // ================= layer 1 =================
    int b = blockIdx.x - L0_BLOCKS;
    uint32_t wI[64], wH[64];
#pragma unroll
    for (int g = 0; g < 4; ++g)
#pragma unroll
      for (int o = 0; o < 2; ++o) {
        size_t R = (size_t)(1024 * g + 8 * b + 2 * w + o) * 1024;
#pragma unroll
        for (int p = 0; p < 8; ++p) {
          int k = l + 64 * p;
          float2_t u1 = *(const float2_t*)&wih1[R + 2 * k];
          float2_t u2 = *(const float2_t*)&whh1[R + 2 * k];
          wI[(2 * g + o) * 8 + p] = packh(u1.x, u1.y);
          wH[(2 * g + o) * 8 + p] = packh(u2.x, u2.y);
        }
      }
    float c1 = 0.f;
    float b1v[4] = {0.f, 0.f, 0.f, 0.f};
    if (l < 2) {
#pragma unroll
      for (int g = 0; g < 4; ++g) {
        int r = 1024 * g + 8 * b + 2 * w + l;
        b1v[g] = b_ih1[r] + b_hh1[r];
      }
    }

    for (int t = 0; t < T_STEPS; ++t) {
      // poll h1(t-1) = tag t (R1 slot t&3) and h0(t) = tag t+1 (R0 slot (t+1)&3)
      {
        const uint64_t* b1p = R1 + ((size_t)(b & 7) * 4 + (size_t)(t & 3)) * 512;
        const uint64_t* b0p = R0 + ((size_t)(8 + (b & 7)) * 4 + (size_t)((t + 1) & 3)) * 512;
        uint64_t v0 = 0, v1 = 0, v2 = 0, v3 = 0;
        bool d0 = false, d1 = false, d2 = false, d3 = false;
        uint32_t tg0 = (uint32_t)(t + 1), tg1 = (uint32_t)t;
        do {
          if (!d0) { v0 = ald64(b0p + tid);       d0 = ((uint32_t)(v0 >> 32) == tg0); }
          if (!d1) { v1 = ald64(b0p + tid + 256); d1 = ((uint32_t)(v1 >> 32) == tg0); }
          if (!d2) { v2 = ald64(b1p + tid);       d2 = ((uint32_t)(v2 >> 32) == tg1); }
          if (!d3) { v3 = ald64(b1p + tid + 256); d3 = ((uint32_t)(v3 >> 32) == tg1); }
        } while (!(d0 && d1 && d2 && d3));
        hL[tid] = (uint32_t)v0;
        hL[tid + 256] = (uint32_t)v1;
        hL[512 + tid] = (uint32_t)v2;
        hL[768 + tid] = (uint32_t)v3;
      }
      __syncthreads();

      uint32_t h0w[8], h1w[8];
#pragma unroll
      for (int p = 0; p < 8; ++p) {
        h0w[p] = hL[l + 64 * p];
        h1w[p] = hL[512 + l + 64 * p];
      }
      float acc[8];
#pragma unroll
      for (int ri = 0; ri < 8; ++ri) acc[ri] = 0.f;
#pragma unroll
      for (int ri = 0; ri < 8; ++ri)
#pragma unroll
        for (int p = 0; p < 8; ++p) {
          acc[ri] = fdot2w(wI[ri * 8 + p], h0w[p], acc[ri]);
          acc[ri] = fdot2w(wH[ri * 8 + p], h1w[p], acc[ri]);
        }
#pragma unroll
      for (int d = 1; d < 64; d <<= 1)
#pragma unroll
        for (int ri = 0; ri < 8; ++ri) acc[ri] += __shfl_xor(acc[ri], d);

      float h = 0.f;
      if (l < 2) {
        float zi = acc[0 + l] + b1v[0];
        float zf = acc[2 + l] + b1v[1];
        float zg = acc[4 + l] + b1v[2];
        float zo = acc[6 + l] + b1v[3];
        float ig = sigf(zi), fg = sigf(zf), gg = tanhf_(zg), og = sigf(zo);
        c1 = fg * c1 + ig * gg;
        h = og * tanhf_(c1);
      }
      float ho = __shfl(h, 1);
      if (l == 0) {
        uint32_t pr = packh(h, ho);
        pairs[w] = pr;
        *(uint32_t*)(hs + (size_t)t * 1024 + 8 * b + 2 * w) = pr;
      }
      __syncthreads();
      if (w == 0 && l < 32) {
        uint64_t val = ((uint64_t)(uint32_t)(t + 1) << 32) | (uint64_t)pairs[l & 3];
        ast64(&R1[((size_t)(l >> 2) * 4 + (size_t)((t + 1) & 3)) * 512 + 4 * b + (l & 3)], val);
      }
    }
  }
}

// ---------------- value head: v[t] = hs[t]·w_val + b_val ----------------
__global__ void k_values(const f16* __restrict__ hs, const float* __restrict__ w_val,
                         const float* __restrict__ b_val, float* __restrict__ outv) {
  int t = blockIdx.x * 4 + (threadIdx.x >> 6);
  int l = threadIdx.x & 63;
  const f16* row = hs + (size_t)t * 1024 + l * 16;
  const float* wv = w_val + l * 16;
  float s = 0.f;
#pragma unroll
  for (int i = 0; i < 16; ++i) s += (float)row[i] * wv[i];
#pragma unroll
  for (int d = 1; d < 64; d <<= 1) s += __shfl_xor(s, d);
  if (l == 0) outv[t] = s + b_val[0];
}

// ---------------- softmax over 512 logits per row, in place ----------------
__global__ void k_softmax(float* __restrict__ out) {
  int t = blockIdx.x * 4 + (threadIdx.x >> 6);
  int l = threadIdx.x & 63;
  float* row = out + (size_t)t * 512;
  float v[8];
  float m = -1e30f;
#pragma unroll
  for (int i = 0; i < 8; ++i) { v[i] = row[l + 64 * i]; m = fmaxf(m, v[i]); }
#pragma unroll
  for (int d = 1; d < 64; d <<= 1) m = fmaxf(m, __shfl_xor(m, d));
  float s = 0.f;
#pragma unroll
  for (int i = 0; i < 8; ++i) { v[i] = __expf(v[i] - m); s += v[i]; }
#pragma unroll
  for (int d = 1; d < 64; d <<= 1) s += __shfl_xor(s, d);
  float inv = 1.f / s;
#pragma unroll
  for (int i = 0; i < 8; ++i) row[l + 64 * i] = v[i] * inv;
}

extern "C" void kernel_launch(void* const* d_in, const int* in_sizes, int n_in,
                              void* d_out, int out_size, void* d_ws, size_t ws_size,
                              hipStream_t stream) {
  const float* x      = (const float*)d_in[0];
  const float* w_ih0  = (const float*)d_in[1];
  const float* w_hh0  = (const float*)d_in[2];
  const float* b_ih0  = (const float*)d_in[3];
  const float* b_hh0  = (const float*)d_in[4];
  const float* w_ih1  = (const float*)d_in[5];
  const float* w_hh1  = (const float*)d_in[6];
  const float* b_ih1  = (const float*)d_in[7];
  const float* b_hh1  = (const float*)d_in[8];
  const float* w_pol  = (const float*)d_in[9];
  const float* b_pol  = (const float*)d_in[10];
  const float* w_val  = (const float*)d_in[11];
  const float* b_val  = (const float*)d_in[12];

  char* ws = (char*)d_ws;
  f16*      Zx  = (f16*)(ws + OFF_ZX);
  f16*      hs  = (f16*)(ws + OFF_HS);
  uint64_t* R0  = (uint64_t*)(ws + OFF_R0);
  uint64_t* R1  = (uint64_t*)(ws + OFF_R1);
  float*    out = (float*)d_out;

  k_init<<<192, 256, 0, stream>>>(R0);
  // Zx0 = x @ w_ih0^T + b_ih0 + b_hh0 : M=8192, N=4096, K=512
  k_gemm<false, true><<<dim3(32, 64), 256, 0, stream>>>(
      (const void*)x, w_ih0, b_ih0, b_hh0, (void*)Zx, 4096, 512, 512);
  k_serial<<<256, 256, 0, stream>>>(Zx, w_hh0, w_ih1, w_hh1, R0, R1, hs, b_ih1, b_hh1);
  // policy logits = hs @ w_pol^T + b_pol : M=8192, N=512, K=1024 -> d_out (f32)
  k_gemm<true, false><<<dim3(4, 64), 256, 0, stream>>>(
      (const void*)hs, w_pol, b_pol, nullptr, (void*)out, 512, 1024, 1024);
  k_values<<<2048, 256, 0, stream>>>(hs, w_val, b_val, out + (size_t)8192 * 512);
  k_softmax<<<2048, 256, 0, stream>>>(out);
}